// Round 3
// baseline (358.649 us; speedup 1.0000x reference)
//
#include <hip/hip_runtime.h>
#include <hip/hip_bf16.h>
#include <hip/hip_cooperative_groups.h>

namespace cg = cooperative_groups;

// Problem constants (from reference)
#define BB 2
#define TT 1024
#define CC 2048
#define NCH 8
#define KLAT 32
#define NKV 4
#define NREP 4
#define DD 128
#define MROWS (BB*TT)          // 2048
#define CSROWS (BB*NCH*KLAT)   // 512
#define NBUCKET 16             // B * NCH
#define TTILE 8                // tokens per attention tile
#define MAXTILES (MROWS/TTILE + NBUCKET)   // 272

typedef unsigned short u16;
typedef __attribute__((ext_vector_type(8))) short bf16x8;   // MFMA A/B frag (4 VGPRs)
typedef __attribute__((ext_vector_type(4))) float f32x4;    // MFMA C/D frag
typedef __attribute__((ext_vector_type(8))) u16 u16x8;

__device__ __forceinline__ u16 f2bf(float f) {
    unsigned int u = __builtin_bit_cast(unsigned int, f);
    u = (u + 0x7FFFu + ((u >> 16) & 1u)) >> 16;   // RNE; inputs finite
    return (u16)u;
}

// async global->LDS, 16B per lane. LDS dest = wave-uniform base + lane*16.
__device__ __forceinline__ void glds16(const u16* g, u16* l) {
    __builtin_amdgcn_global_load_lds(
        (const __attribute__((address_space(1))) void*)g,
        (__attribute__((address_space(3))) void*)l, 16, 0, 0);
}

// ================= prep unit bodies (phase 0) =================
#define PB_SORT 0
#define PB_X    1                       // 2048 units: cvt x
#define PB_CS   (PB_X + 2048)           // 512: cvt cs
#define PB_WQ   (PB_CS + 512)           // 1024: tcvt Wq (32 x 32)
#define PB_WK   (PB_WQ + 1024)          // 256:  tcvt Wk (8 x 32)
#define PB_WV   (PB_WK + 256)           // 256:  tcvt Wv (8 x 32)
#define PB_WO   (PB_WV + 256)           // 1024: tcvt Wo (32 x 32)
#define PB_END  (PB_WO + 1024)          // 5121

__device__ __forceinline__ void cvt_body(const float* __restrict__ in, u16* __restrict__ out,
                                         int blk, int tid) {
    int i = (blk * 256 + tid) * 8;
    float4 a = *(const float4*)(in + i);
    float4 b = *(const float4*)(in + i + 4);
    u16x8 o;
    o[0]=f2bf(a.x); o[1]=f2bf(a.y); o[2]=f2bf(a.z); o[3]=f2bf(a.w);
    o[4]=f2bf(b.x); o[5]=f2bf(b.y); o[6]=f2bf(b.z); o[7]=f2bf(b.w);
    *(u16x8*)(out + i) = o;
}

__device__ __forceinline__ void tcvt_body(const float* __restrict__ in, u16* __restrict__ out,
                                          int R, int C, int bx, int by, int tid,
                                          u16 (*tile)[65]) {
    const int c0 = bx * 64, r0 = by * 64;
    const int tx = tid & 15, ty = tid >> 4;
#pragma unroll
    for (int p = 0; p < 4; ++p) {
        int r = p * 16 + ty;
        float4 v = *(const float4*)(in + (size_t)(r0 + r) * C + c0 + tx * 4);
        tile[tx*4+0][r] = f2bf(v.x);
        tile[tx*4+1][r] = f2bf(v.y);
        tile[tx*4+2][r] = f2bf(v.z);
        tile[tx*4+3][r] = f2bf(v.w);
    }
    __syncthreads();
    const int oc = tid >> 2, op = tid & 3;
    u16* dst = out + (size_t)(c0 + oc) * R + r0 + op * 16;
    u16x8 v0, v1;
#pragma unroll
    for (int j = 0; j < 8; ++j) { v0[j] = tile[oc][op*16 + j]; v1[j] = tile[oc][op*16 + 8 + j]; }
    *(u16x8*)dst = v0;
    *(u16x8*)(dst + 8) = v1;
}

// ========== 4-stage single-barrier pipelined bf16 GEMM core, 128x128 tile ==========
// A/Bt pre-offset to block panel start (row-major, leading dim GK=2048).
// BK=32, 4 LDS buffers (64 KB), lookahead 3 stages, kiters K-steps.
// Safety: glds at iter k overwrites buf (k-1)%4; every wave past barrier(k)
// has lgkm-waited its stage-(k-1) ds_reads -> no WAR race, one barrier/iter.
// Prefetch overreads <=192 B past each panel K-slice (mapped neighbors).
#define GK 2048
__device__ __forceinline__ void gemm_core(const u16* __restrict__ A, const u16* __restrict__ Bt,
                                          u16* lds, f32x4 (*acc)[4], int kiters)
{
    constexpr int BK = 32, STAGE = 8192;   // (128+128)*32 u16 = 16 KB
    const int tid  = threadIdx.x;
    const int wave = tid >> 6;
    const int lane = tid & 63;
    const int wm = (wave & 1) * 64;
    const int wn = (wave >> 1) * 64;
    const int ml = lane & 15;
    const int quad = lane >> 4;

#pragma unroll
    for (int i = 0; i < 4; ++i)
#pragma unroll
        for (int j = 0; j < 4; ++j) acc[i][j] = (f32x4){0.f, 0.f, 0.f, 0.f};

    const u16* aptr = A  + (size_t)(tid >> 2) * GK + (tid & 3) * 8;
    const u16* bptr = Bt + (size_t)(tid >> 2) * GK + (tid & 3) * 8;
    const int aoff = wave * 512;
    const int boff = 128 * BK + wave * 512;

    // prologue: stages 0,1,2 (12 outstanding loads / wave)
#pragma unroll
    for (int s = 0; s < 3; ++s) {
        u16* base = lds + s * STAGE;
        glds16(aptr + s * BK,                   base + aoff);
        glds16(aptr + (size_t)64 * GK + s * BK, base + aoff + 2048);
        glds16(bptr + s * BK,                   base + boff);
        glds16(bptr + (size_t)64 * GK + s * BK, base + boff + 2048);
    }

    for (int it = 0; it < kiters; ++it) {
        u16* cbase = lds + (it & 3) * STAGE;
        asm volatile("s_waitcnt vmcnt(8)" ::: "memory");   // oldest stage resident
        asm volatile("s_barrier" ::: "memory");
        {   // issue stage it+3 into buf (it+3)%4 == (it-1)%4 (just freed)
            const int kn = (it + 3) * BK;
            u16* nbase = lds + ((it + 3) & 3) * STAGE;
            glds16(aptr + kn,                   nbase + aoff);
            glds16(aptr + (size_t)64 * GK + kn, nbase + aoff + 2048);
            glds16(bptr + kn,                   nbase + boff);
            glds16(bptr + (size_t)64 * GK + kn, nbase + boff + 2048);
        }
        bf16x8 afr[4], bfr[4];
#pragma unroll
        for (int i = 0; i < 4; ++i)
            afr[i] = *(const bf16x8*)&cbase[(wm + i * 16 + ml) * BK + quad * 8];
#pragma unroll
        for (int j = 0; j < 4; ++j)
            bfr[j] = *(const bf16x8*)&cbase[128 * BK + (wn + j * 16 + ml) * BK + quad * 8];
#pragma unroll
        for (int i = 0; i < 4; ++i)
#pragma unroll
            for (int j = 0; j < 4; ++j)
                acc[i][j] = __builtin_amdgcn_mfma_f32_16x16x32_bf16(afr[i], bfr[j], acc[i][j], 0, 0, 0);
    }
    asm volatile("s_waitcnt vmcnt(0)" ::: "memory");   // drain tail prefetches before LDS reuse
}

// ================= single fused cooperative kernel =================
// 256 blocks x 256 threads, 64 KB static LDS, 4 grid syncs.
// ph0 prep -> ph1 qGEMM + kv split-K sliver -> ph2 combine -> ph3 attn -> ph4 outGEMM
__global__ void __launch_bounds__(256)
main_kernel(const float* __restrict__ x, const float* __restrict__ cs,
            const int* __restrict__ cm,
            const float* __restrict__ Wq, const float* __restrict__ Wk,
            const float* __restrict__ Wv, const float* __restrict__ Wo,
            const float* __restrict__ gate, float* __restrict__ out,
            u16* __restrict__ xb, u16* __restrict__ csb,
            u16* __restrict__ wqt, u16* __restrict__ wkvt, u16* __restrict__ wot,
            u16* __restrict__ qb, float* __restrict__ kvp,
            u16* __restrict__ kb, u16* __restrict__ vt, u16* __restrict__ yb,
            int* __restrict__ sorted, int4* __restrict__ tiles, int* __restrict__ ntiles)
{
    __shared__ __align__(16) u16 sh[32768];   // 64 KB, reused by every phase
    cg::grid_group grid = cg::this_grid();
    const int bid = blockIdx.x;
    const int tid = threadIdx.x;
    const int wave = tid >> 6, lane = tid & 63;
    const int ml = lane & 15, quad = lane >> 4;

    // ---------------- phase 0: prep (5121 units over 256 blocks) ----------------
    {
        u16 (*tile)[65] = (u16(*)[65])sh;           // 4160 u16
        int* cnt = (int*)(sh + 8192);               // sort scratch (disjoint from tile)
        int* cur = cnt + NBUCKET;
        for (int u = bid; u < PB_END; u += 256) {
            __syncthreads();                        // LDS reuse across units
            if (u == PB_SORT) {
                if (tid < NBUCKET) cnt[tid] = 0;
                __syncthreads();
                for (int i = tid; i < MROWS; i += 256) {
                    int bkt = ((i >> 10) << 3) | cm[i];
                    atomicAdd(&cnt[bkt], 1);
                }
                __syncthreads();
                if (tid == 0) {
                    int off = 0, nt = 0;
                    for (int b2 = 0; b2 < NBUCKET; ++b2) {
                        cur[b2] = off;
                        for (int o = 0; o < cnt[b2]; o += TTILE)
                            tiles[nt++] = make_int4(b2, off + o, min(TTILE, cnt[b2] - o), 0);
                        off += cnt[b2];
                    }
                    *ntiles = nt;
                }
                __syncthreads();
                for (int i = tid; i < MROWS; i += 256) {
                    int bkt = ((i >> 10) << 3) | cm[i];
                    int pos = atomicAdd(&cur[bkt], 1);
                    sorted[pos] = i;
                }
            } else if (u < PB_CS) {
                cvt_body(x, xb, u - PB_X, tid);
            } else if (u < PB_WQ) {
                cvt_body(cs, csb, u - PB_CS, tid);
            } else if (u < PB_WK) {
                int b2 = u - PB_WQ;
                tcvt_body(Wq, wqt, CC, CC, b2 & 31, b2 >> 5, tid, tile);
            } else if (u < PB_WV) {
                int b2 = u - PB_WK;
                tcvt_body(Wk, wkvt, CC, 512, b2 & 7, b2 >> 3, tid, tile);
            } else if (u < PB_WO) {
                int b2 = u - PB_WV;
                tcvt_body(Wv, wkvt + (size_t)512 * CC, CC, 512, b2 & 7, b2 >> 3, tid, tile);
            } else {
                int b2 = u - PB_WO;
                tcvt_body(Wo, wot, CC, CC, b2 & 31, b2 >> 5, tid, tile);
            }
        }
    }
    grid.sync();

    // ---------------- phase 1: q-GEMM tile + kv split-K sliver ----------------
    // 2D XCD-local tiling: XCD x owns a 4(m) x 8(n) region -> L2-local A and B panels.
    {
        const int xcd = bid & 7, l = bid >> 3;
        const int wm = (wave & 1) * 64, wn = (wave >> 1) * 64;
        const int m0 = ((xcd & 3) * 4 + (l & 3)) * 128;
        const int n0 = ((xcd >> 2) * 8 + (l >> 2)) * 128;
        f32x4 acc[4][4];
        gemm_core(xb + (size_t)m0 * GK, wqt + (size_t)n0 * GK, sh, acc, 64);
#pragma unroll
        for (int i = 0; i < 4; ++i)
#pragma unroll
            for (int j = 0; j < 4; ++j)
#pragma unroll
                for (int rr = 0; rr < 4; ++rr) {
                    int gr = m0 + wm + i * 16 + quad * 4 + rr;
                    int gc = n0 + wn + j * 16 + ml;
                    qb[(size_t)gr * 2048 + gc] = f2bf(acc[i][j][rr]);
                }
        __syncthreads();   // all waves done with LDS before kv prologue overwrites

        // kv chunk: XCD-local: n-panel = xcd, m = l&3, kslice = l>>2
        const int m0k = (l & 3) * 128, n0k = xcd * 128, ks = l >> 2;
        gemm_core(csb + (size_t)m0k * GK + ks * 256,
                  wkvt + (size_t)n0k * GK + ks * 256, sh, acc, 8);
        float* dst = kvp + (size_t)ks * 512 * 1024;
#pragma unroll
        for (int i = 0; i < 4; ++i)
#pragma unroll
            for (int j = 0; j < 4; ++j)
#pragma unroll
                for (int rr = 0; rr < 4; ++rr) {
                    int gr = m0k + wm + i * 16 + quad * 4 + rr;
                    int gc = n0k + wn + j * 16 + ml;
                    dst[(size_t)gr * 1024 + gc] = acc[i][j][rr];
                }
    }
    grid.sync();

    // ---------------- phase 2: kv split-K combine -> kb / vt ----------------
    {
        int idx = (bid * 256 + tid) * 8;            // 65536 threads x 8 = 512*1024
        int r = idx >> 10, c0 = idx & 1023;
        float4 sa = *(const float4*)(kvp + idx);
        float4 sb = *(const float4*)(kvp + idx + 4);
#pragma unroll
        for (int ks = 1; ks < 8; ++ks) {
            const float* p = kvp + (size_t)ks * 524288 + idx;
            float4 pa = *(const float4*)p;
            float4 pb = *(const float4*)(p + 4);
            sa.x += pa.x; sa.y += pa.y; sa.z += pa.z; sa.w += pa.w;
            sb.x += pb.x; sb.y += pb.y; sb.z += pb.z; sb.w += pb.w;
        }
        float v8[8] = {sa.x, sa.y, sa.z, sa.w, sb.x, sb.y, sb.z, sb.w};
        if (c0 < 512) {
#pragma unroll
            for (int t = 0; t < 8; ++t)
                kb[(size_t)r * 512 + c0 + t] = f2bf(v8[t]);
        } else {
            int bn = r >> 5, lat = r & 31;
#pragma unroll
            for (int t = 0; t < 8; ++t) {
                int c = c0 + t;
                int g = (c - 512) >> 7, d = (c - 512) & 127;
                vt[(((size_t)bn * 4 + g) << 12) + (d << 5) + lat] = f2bf(v8[t]);
            }
        }
    }
    grid.sync();

    // ---------------- phase 3: attention (block = tile, wave = group) ----------------
    // K/V read direct from global (L2-resident, staging was an identity map).
    // Only p_lds (cross-lane P redistribution) kept, per-wave slice, lgkm-ordered.
    {
        u16* pw = sh + wave * 1296;          // 32*40 u16 P slice (2560 B), 16B aligned
        int* tokw = (int*)(pw + 1280);       // 8 ints per wave
        const int nt = *ntiles;
        const int g = wave;
#pragma unroll 1
        for (int pass = 0; pass < 2; ++pass) {
            const int tile = pass * 256 + bid;
            if (tile >= MAXTILES || tile >= nt) continue;
            const int4 td = tiles[tile];
            const int bucket = td.x, start = td.y, cnt2 = td.z;
            if (lane < TTILE) tokw[lane] = (lane < cnt2) ? sorted[start + lane] : -1;
            asm volatile("s_waitcnt lgkmcnt(0)" ::: "memory");
            __builtin_amdgcn_sched_barrier(0);

            const u16* ksrc = kb + (size_t)bucket * 32 * 512 + g * 128;
            const u16* vsrc = vt + ((size_t)bucket * 4 + g) * 4096;

            f32x4 sc[2][2];
#pragma unroll
            for (int i = 0; i < 2; ++i)
#pragma unroll
                for (int j = 0; j < 2; ++j) sc[i][j] = (f32x4){0.f, 0.f, 0.f, 0.f};
            const int tokA = tokw[ml & 7];
            const u16* qrow = qb + (size_t)(tokA >= 0 ? tokA : 0) * 2048 + g * 512 + (ml >> 3) * 128;
#pragma unroll
            for (int s = 0; s < 4; ++s) {
                bf16x8 bfr0 = *(const bf16x8*)(ksrc + (size_t)ml * 512 + s * 32 + quad * 8);
                bf16x8 bfr1 = *(const bf16x8*)(ksrc + (size_t)(16 + ml) * 512 + s * 32 + quad * 8);
#pragma unroll
                for (int i = 0; i < 2; ++i) {
                    bf16x8 afr = *(const bf16x8*)(qrow + i * 256 + s * 32 + quad * 8);
                    sc[i][0] = __builtin_amdgcn_mfma_f32_16x16x32_bf16(afr, bfr0, sc[i][0], 0, 0, 0);
                    sc[i][1] = __builtin_amdgcn_mfma_f32_16x16x32_bf16(afr, bfr1, sc[i][1], 0, 0, 0);
                }
            }

            const float scale = 0.088388347648318447f;   // 1/sqrt(128)
#pragma unroll
            for (int i = 0; i < 2; ++i)
#pragma unroll
                for (int reg = 0; reg < 4; ++reg) {
                    float s0 = sc[i][0][reg] * scale;
                    float s1 = sc[i][1][reg] * scale;
                    float mx = fmaxf(s0, s1);
                    mx = fmaxf(mx, __shfl_xor(mx, 1));
                    mx = fmaxf(mx, __shfl_xor(mx, 2));
                    mx = fmaxf(mx, __shfl_xor(mx, 4));
                    mx = fmaxf(mx, __shfl_xor(mx, 8));
                    float e0 = __expf(s0 - mx), e1 = __expf(s1 - mx);
                    float sm = e0 + e1;
                    sm += __shfl_xor(sm, 1);
                    sm += __shfl_xor(sm, 2);
                    sm += __shfl_xor(sm, 4);
                    sm += __shfl_xor(sm, 8);
                    float inv = 1.0f / sm;
                    int prow = i * 16 + quad * 4 + reg;
                    pw[prow * 40 + ml]      = f2bf(e0 * inv);
                    pw[prow * 40 + 16 + ml] = f2bf(e1 * inv);
                }
            asm volatile("s_waitcnt lgkmcnt(0)" ::: "memory");
            __builtin_amdgcn_sched_barrier(0);

            bf16x8 pfr[2];
            pfr[0] = *(const bf16x8*)&pw[ml * 40 + quad * 8];
            pfr[1] = *(const bf16x8*)&pw[(16 + ml) * 40 + quad * 8];
#pragma unroll
            for (int i = 0; i < 2; ++i)
#pragma unroll
                for (int j = 0; j < 8; ++j) {
                    bf16x8 vfr = *(const bf16x8*)(vsrc + (size_t)(j * 16 + ml) * 32 + quad * 8);
                    f32x4 o = (f32x4){0.f, 0.f, 0.f, 0.f};
                    o = __builtin_amdgcn_mfma_f32_16x16x32_bf16(pfr[i], vfr, o, 0, 0, 0);
#pragma unroll
                    for (int reg = 0; reg < 4; ++reg) {
                        int m = quad * 4 + reg;
                        int tok = tokw[m & 7];
                        if (tok >= 0) {
                            int r = i * 2 + (m >> 3);
                            yb[(size_t)tok * 2048 + g * 512 + r * 128 + j * 16 + ml] = f2bf(o[reg]);
                        }
                    }
                }
        }
    }
    grid.sync();

    // ---------------- phase 4: out = (y @ Wo) * tanh(gate) ----------------
    {
        const int xcd = bid & 7, l = bid >> 3;
        const int wm = (wave & 1) * 64, wn = (wave >> 1) * 64;
        const int m0 = ((xcd & 3) * 4 + (l & 3)) * 128;
        const int n0 = ((xcd >> 2) * 8 + (l >> 2)) * 128;
        f32x4 acc[4][4];
        gemm_core(yb + (size_t)m0 * GK, wot + (size_t)n0 * GK, sh, acc, 64);
        const float scl = tanhf(gate[0]);
#pragma unroll
        for (int i = 0; i < 4; ++i)
#pragma unroll
            for (int j = 0; j < 4; ++j)
#pragma unroll
                for (int rr = 0; rr < 4; ++rr) {
                    int gr = m0 + wm + i * 16 + quad * 4 + rr;
                    int gc = n0 + wn + j * 16 + ml;
                    out[(size_t)gr * 2048 + gc] = acc[i][j][rr] * scl;
                }
    }
}

extern "C" void kernel_launch(void* const* d_in, const int* in_sizes, int n_in,
                              void* d_out, int out_size, void* d_ws, size_t ws_size,
                              hipStream_t stream) {
    const float* x    = (const float*)d_in[0];
    const float* cs   = (const float*)d_in[1];
    const int*   cm   = (const int*)d_in[2];
    const float* Wq   = (const float*)d_in[3];
    const float* Wk   = (const float*)d_in[4];
    const float* Wv   = (const float*)d_in[5];
    const float* Wo   = (const float*)d_in[6];
    const float* gate = (const float*)d_in[7];
    float* out = (float*)d_out;

    // workspace layout (16B aligned). Every GEMM A/Bt panel is followed by
    // mapped workspace (pipelined prefetch overreads <=192 B per row).
    // kvp (16 MB f32 split-K partials) OVERLAYS yb: kvp live ph1->ph2 only;
    // yb written in ph3 strictly after ph2 (grid.sync between).
    char* w = (char*)d_ws;
    u16* xb   = (u16*)w;  w += (size_t)MROWS * CC * 2;        // 8.4 MB
    u16* wqt  = (u16*)w;  w += (size_t)CC * CC * 2;           // 8.4 MB
    u16* wot  = (u16*)w;  w += (size_t)CC * CC * 2;           // 8.4 MB
    u16* qb   = (u16*)w;  w += (size_t)MROWS * CC * 2;        // 8.4 MB
    u16* csb  = (u16*)w;  w += (size_t)CSROWS * CC * 2;       // 2.1 MB
    u16* wkvt = (u16*)w;  w += (size_t)1024 * CC * 2;         // 4.2 MB
    u16* kb   = (u16*)w;  w += (size_t)CSROWS * 512 * 2;      // 0.5 MB
    u16* vt   = (u16*)w;  w += (size_t)64 * 128 * 32 * 2;     // 0.5 MB
    int* sorted = (int*)w; w += (size_t)MROWS * 4;
    int4* tiles = (int4*)w; w += (size_t)MAXTILES * 16;
    int* ntiles = (int*)w;  w += 4096;
    float* kvp = (float*)w;                                   // 16 MB (8 x 512 x 1024 f32)
    u16* yb = (u16*)w;      w += (size_t)8 * 512 * 1024 * 4;  // yb (8.4 MB) inside kvp region

    void* kargs[] = {
        (void*)&x, (void*)&cs, (void*)&cm, (void*)&Wq, (void*)&Wk, (void*)&Wv,
        (void*)&Wo, (void*)&gate, (void*)&out,
        (void*)&xb, (void*)&csb, (void*)&wqt, (void*)&wkvt, (void*)&wot,
        (void*)&qb, (void*)&kvp, (void*)&kb, (void*)&vt, (void*)&yb,
        (void*)&sorted, (void*)&tiles, (void*)&ntiles
    };
    hipLaunchCooperativeKernel((const void*)main_kernel, dim3(256), dim3(256),
                               kargs, 0, stream);
}

// Round 4
// 189.209 us; speedup vs baseline: 1.8955x; 1.8955x over previous
//
#include <hip/hip_runtime.h>
#include <hip/hip_bf16.h>

// Problem constants (from reference)
#define BB 2
#define TT 1024
#define CC 2048
#define NCH 8
#define KLAT 32
#define NKV 4
#define NREP 4
#define DD 128
#define MROWS (BB*TT)          // 2048
#define CSROWS (BB*NCH*KLAT)   // 512
#define NBUCKET 16             // B * NCH
#define TTILE 8                // tokens per attention tile
#define MAXTILES (MROWS/TTILE + NBUCKET)   // 272

typedef unsigned short u16;
typedef __attribute__((ext_vector_type(8))) short bf16x8;   // MFMA A/B frag (4 VGPRs)
typedef __attribute__((ext_vector_type(4))) float f32x4;    // MFMA C/D frag
typedef __attribute__((ext_vector_type(8))) u16 u16x8;

__device__ __forceinline__ u16 f2bf(float f) {
    unsigned int u = __builtin_bit_cast(unsigned int, f);
    u = (u + 0x7FFFu + ((u >> 16) & 1u)) >> 16;   // RNE; inputs finite
    return (u16)u;
}

// async global->LDS, 16B per lane. LDS dest = wave-uniform base + lane*16.
__device__ __forceinline__ void glds16(const u16* g, u16* l) {
    __builtin_amdgcn_global_load_lds(
        (const __attribute__((address_space(1))) void*)g,
        (__attribute__((address_space(3))) void*)l, 16, 0, 0);
}

// ================= prep: sort + converts + weight transposes, one launch =================
#define PB_SORT 0
#define PB_X    1                       // 2048 blocks: cvt x
#define PB_CS   (PB_X + 2048)           // 512: cvt cs
#define PB_WQ   (PB_CS + 512)           // 1024: tcvt Wq (32 x 32)
#define PB_WK   (PB_WQ + 1024)          // 256:  tcvt Wk (8 x 32)
#define PB_WV   (PB_WK + 256)           // 256:  tcvt Wv (8 x 32)
#define PB_WO   (PB_WV + 256)           // 1024: tcvt Wo (32 x 32)
#define PB_END  (PB_WO + 1024)          // 5121

__device__ __forceinline__ void cvt_body(const float* __restrict__ in, u16* __restrict__ out,
                                         int blk, int tid) {
    int i = (blk * 256 + tid) * 8;
    float4 a = *(const float4*)(in + i);
    float4 b = *(const float4*)(in + i + 4);
    u16x8 o;
    o[0]=f2bf(a.x); o[1]=f2bf(a.y); o[2]=f2bf(a.z); o[3]=f2bf(a.w);
    o[4]=f2bf(b.x); o[5]=f2bf(b.y); o[6]=f2bf(b.z); o[7]=f2bf(b.w);
    *(u16x8*)(out + i) = o;
}

__device__ __forceinline__ void tcvt_body(const float* __restrict__ in, u16* __restrict__ out,
                                          int R, int C, int bx, int by, int tid,
                                          u16 (*tile)[65]) {
    const int c0 = bx * 64, r0 = by * 64;
    const int tx = tid & 15, ty = tid >> 4;
#pragma unroll
    for (int p = 0; p < 4; ++p) {
        int r = p * 16 + ty;
        float4 v = *(const float4*)(in + (size_t)(r0 + r) * C + c0 + tx * 4);
        tile[tx*4+0][r] = f2bf(v.x);
        tile[tx*4+1][r] = f2bf(v.y);
        tile[tx*4+2][r] = f2bf(v.z);
        tile[tx*4+3][r] = f2bf(v.w);
    }
    __syncthreads();
    const int oc = tid >> 2, op = tid & 3;
    u16* dst = out + (size_t)(c0 + oc) * R + r0 + op * 16;
    u16x8 v0, v1;
#pragma unroll
    for (int j = 0; j < 8; ++j) { v0[j] = tile[oc][op*16 + j]; v1[j] = tile[oc][op*16 + 8 + j]; }
    *(u16x8*)dst = v0;
    *(u16x8*)(dst + 8) = v1;
}

__global__ void __launch_bounds__(256)
prep_kernel(const float* __restrict__ x, const float* __restrict__ cs,
            const int* __restrict__ cm,
            const float* __restrict__ Wq, const float* __restrict__ Wk,
            const float* __restrict__ Wv, const float* __restrict__ Wo,
            u16* __restrict__ xb, u16* __restrict__ csb,
            u16* __restrict__ wqt, u16* __restrict__ wkvt, u16* __restrict__ wot,
            int* __restrict__ sorted, int4* __restrict__ tiles, int* __restrict__ ntiles)
{
    __shared__ u16 tile[64][65];
    __shared__ int cnt[NBUCKET], cur[NBUCKET];
    const int bid = blockIdx.x;
    const int tid = threadIdx.x;

    if (bid == PB_SORT) {
        if (tid < NBUCKET) cnt[tid] = 0;
        __syncthreads();
        for (int i = tid; i < MROWS; i += 256) {
            int bkt = ((i >> 10) << 3) | cm[i];
            atomicAdd(&cnt[bkt], 1);
        }
        __syncthreads();
        if (tid == 0) {
            int off = 0, nt = 0;
            for (int b2 = 0; b2 < NBUCKET; ++b2) {
                cur[b2] = off;
                for (int o = 0; o < cnt[b2]; o += TTILE)
                    tiles[nt++] = make_int4(b2, off + o, min(TTILE, cnt[b2] - o), 0);
                off += cnt[b2];
            }
            *ntiles = nt;
        }
        __syncthreads();
        for (int i = tid; i < MROWS; i += 256) {
            int bkt = ((i >> 10) << 3) | cm[i];
            int pos = atomicAdd(&cur[bkt], 1);
            sorted[pos] = i;
        }
    } else if (bid < PB_CS) {
        cvt_body(x, xb, bid - PB_X, tid);
    } else if (bid < PB_WQ) {
        cvt_body(cs, csb, bid - PB_CS, tid);
    } else if (bid < PB_WK) {
        int b2 = bid - PB_WQ;
        tcvt_body(Wq, wqt, CC, CC, b2 & 31, b2 >> 5, tid, tile);
    } else if (bid < PB_WV) {
        int b2 = bid - PB_WK;
        tcvt_body(Wk, wkvt, CC, 512, b2 & 7, b2 >> 3, tid, tile);
    } else if (bid < PB_WO) {
        int b2 = bid - PB_WV;
        tcvt_body(Wv, wkvt + (size_t)512 * CC, CC, 512, b2 & 7, b2 >> 3, tid, tile);
    } else {
        int b2 = bid - PB_WO;
        tcvt_body(Wo, wot, CC, CC, b2 & 31, b2 >> 5, tid, tile);
    }
}

// ========== 4-stage single-barrier pipelined bf16 GEMM core, 128x128 tile ==========
// A/Bt pre-offset to block panel start (row-major, leading dim GK=2048).
// BK=32, 4 LDS buffers (64 KB), lookahead 3 stages, kiters K-steps.
// Safety: glds at iter k overwrites buf (k-1)%4; every wave past barrier(k)
// has lgkm-waited its stage-(k-1) ds_reads -> no WAR race, one barrier/iter.
// Prefetch overreads <=192 B past each panel K-slice (mapped neighbors).
#define GK 2048
__device__ __forceinline__ void gemm_core(const u16* __restrict__ A, const u16* __restrict__ Bt,
                                          u16* lds, f32x4 (*acc)[4], int kiters)
{
    constexpr int BK = 32, STAGE = 8192;   // (128+128)*32 u16 = 16 KB
    const int tid  = threadIdx.x;
    const int wave = tid >> 6;
    const int lane = tid & 63;
    const int wm = (wave & 1) * 64;
    const int wn = (wave >> 1) * 64;
    const int ml = lane & 15;
    const int quad = lane >> 4;

#pragma unroll
    for (int i = 0; i < 4; ++i)
#pragma unroll
        for (int j = 0; j < 4; ++j) acc[i][j] = (f32x4){0.f, 0.f, 0.f, 0.f};

    const u16* aptr = A  + (size_t)(tid >> 2) * GK + (tid & 3) * 8;
    const u16* bptr = Bt + (size_t)(tid >> 2) * GK + (tid & 3) * 8;
    const int aoff = wave * 512;
    const int boff = 128 * BK + wave * 512;

    // prologue: stages 0,1,2 (12 outstanding loads / wave)
#pragma unroll
    for (int s = 0; s < 3; ++s) {
        u16* base = lds + s * STAGE;
        glds16(aptr + s * BK,                   base + aoff);
        glds16(aptr + (size_t)64 * GK + s * BK, base + aoff + 2048);
        glds16(bptr + s * BK,                   base + boff);
        glds16(bptr + (size_t)64 * GK + s * BK, base + boff + 2048);
    }

    for (int it = 0; it < kiters; ++it) {
        u16* cbase = lds + (it & 3) * STAGE;
        asm volatile("s_waitcnt vmcnt(8)" ::: "memory");   // oldest stage resident
        asm volatile("s_barrier" ::: "memory");
        {   // issue stage it+3 into buf (it+3)%4 == (it-1)%4 (just freed)
            const int kn = (it + 3) * BK;
            u16* nbase = lds + ((it + 3) & 3) * STAGE;
            glds16(aptr + kn,                   nbase + aoff);
            glds16(aptr + (size_t)64 * GK + kn, nbase + aoff + 2048);
            glds16(bptr + kn,                   nbase + boff);
            glds16(bptr + (size_t)64 * GK + kn, nbase + boff + 2048);
        }
        bf16x8 afr[4], bfr[4];
#pragma unroll
        for (int i = 0; i < 4; ++i)
            afr[i] = *(const bf16x8*)&cbase[(wm + i * 16 + ml) * BK + quad * 8];
#pragma unroll
        for (int j = 0; j < 4; ++j)
            bfr[j] = *(const bf16x8*)&cbase[128 * BK + (wn + j * 16 + ml) * BK + quad * 8];
#pragma unroll
        for (int i = 0; i < 4; ++i)
#pragma unroll
            for (int j = 0; j < 4; ++j)
                acc[i][j] = __builtin_amdgcn_mfma_f32_16x16x32_bf16(afr[i], bfr[j], acc[i][j], 0, 0, 0);
    }
    asm volatile("s_waitcnt vmcnt(0)" ::: "memory");   // drain tail prefetches before LDS reuse
}

// ---------------- q-GEMM (256 blocks, perfect pack) + uniform kv split-K sliver ----------------
// kv-GEMM (512x1024x2048) = 32 tiles of 128^2 x split-K-8 = 256 chunks of 8 iters;
// block b does q-tile swz(b) (64 iters) then kv chunk b (8 iters -> f32 partials).
__global__ void __launch_bounds__(256)
gemm_qkv_kernel(const u16* __restrict__ xb, const u16* __restrict__ wqt, u16* __restrict__ qb,
                const u16* __restrict__ csb, const u16* __restrict__ wkvt,
                float* __restrict__ kvp)
{
    constexpr int STAGE = 8192;
    __shared__ u16 lds[4 * STAGE];   // 64 KB
    const int bid = blockIdx.x;      // 0..255
    const int tid = threadIdx.x;
    const int wave = tid >> 6, lane = tid & 63;
    const int wm = (wave & 1) * 64, wn = (wave >> 1) * 64;
    const int ml = lane & 15, quad = lane >> 4;

    // XCD-chunked swizzle (256%8==0, bijective): XCD x gets n-panels {2x,2x+1}
    const int swz = (bid & 7) * 32 + (bid >> 3);
    const int m0 = (swz & 15) * 128, n0 = (swz >> 4) * 128;

    f32x4 acc[4][4];
    gemm_core(xb + (size_t)m0 * GK, wqt + (size_t)n0 * GK, lds, acc, 64);

#pragma unroll
    for (int i = 0; i < 4; ++i)
#pragma unroll
        for (int j = 0; j < 4; ++j)
#pragma unroll
            for (int rr = 0; rr < 4; ++rr) {
                int gr = m0 + wm + i * 16 + quad * 4 + rr;
                int gc = n0 + wn + j * 16 + ml;
                qb[(size_t)gr * 2048 + gc] = f2bf(acc[i][j][rr]);
            }

    __syncthreads();   // all waves done reading LDS before kv prologue overwrites

    // kv chunk: tile = bid>>3 (m 0..3, n 0..7), kslice = bid&7 (K-range ks*256..+256)
    const int tile = bid >> 3, ks = bid & 7;
    const int m0k = (tile & 3) * 128, n0k = (tile >> 2) * 128;
    gemm_core(csb + (size_t)m0k * GK + ks * 256,
              wkvt + (size_t)n0k * GK + ks * 256, lds, acc, 8);

    float* dst = kvp + (size_t)ks * 512 * 1024;
#pragma unroll
    for (int i = 0; i < 4; ++i)
#pragma unroll
        for (int j = 0; j < 4; ++j)
#pragma unroll
            for (int rr = 0; rr < 4; ++rr) {
                int gr = m0k + wm + i * 16 + quad * 4 + rr;
                int gc = n0k + wn + j * 16 + ml;
                dst[(size_t)gr * 1024 + gc] = acc[i][j][rr];
            }
}

// ---------------- kv split-K combine: sum 8 f32 slices -> kb / vt (bf16), 8-wide ----------------
__global__ void __launch_bounds__(256)
kv_combine_kernel(const float* __restrict__ kvp, u16* __restrict__ kb, u16* __restrict__ vt)
{
    const int idx = (blockIdx.x * 256 + threadIdx.x) * 8;   // over 512*1024
    const int r = idx >> 10, c0 = idx & 1023;
    float4 sa = *(const float4*)(kvp + idx);
    float4 sb = *(const float4*)(kvp + idx + 4);
#pragma unroll
    for (int ks = 1; ks < 8; ++ks) {
        const float* p = kvp + (size_t)ks * 524288 + idx;
        float4 pa = *(const float4*)p;
        float4 pb = *(const float4*)(p + 4);
        sa.x += pa.x; sa.y += pa.y; sa.z += pa.z; sa.w += pa.w;
        sb.x += pb.x; sb.y += pb.y; sb.z += pb.z; sb.w += pb.w;
    }
    float v8[8] = {sa.x, sa.y, sa.z, sa.w, sb.x, sb.y, sb.z, sb.w};
    if (c0 < 512) {   // 512 boundary is a multiple of 8: branch uniform per thread
#pragma unroll
        for (int t = 0; t < 8; ++t)
            kb[(size_t)r * 512 + c0 + t] = f2bf(v8[t]);
    } else {
        int bn = r >> 5, lat = r & 31;
#pragma unroll
        for (int t = 0; t < 8; ++t) {
            int c = c0 + t;
            int g = (c - 512) >> 7, d = (c - 512) & 127;
            vt[(((size_t)bn * 4 + g) << 12) + (d << 5) + lat] = f2bf(v8[t]);
        }
    }
}

// ---------------- out = (y @ Wo) * tanh(gate) ----------------
__global__ void __launch_bounds__(256)
gemm_out_kernel(const u16* __restrict__ yb, const u16* __restrict__ wot,
                float* __restrict__ out, const float* __restrict__ gate)
{
    constexpr int STAGE = 8192;
    __shared__ u16 lds[4 * STAGE];   // 64 KB
    const int tid = threadIdx.x;
    const int wave = tid >> 6, lane = tid & 63;
    const int wm = (wave & 1) * 64, wn = (wave >> 1) * 64;
    const int ml = lane & 15, quad = lane >> 4;

    const int bid = blockIdx.x;
    const int swz = (bid & 7) * 32 + (bid >> 3);
    const int m0 = (swz & 15) * 128, n0 = (swz >> 4) * 128;

    f32x4 acc[4][4];
    gemm_core(yb + (size_t)m0 * GK, wot + (size_t)n0 * GK, lds, acc, 64);

    const float scl = tanhf(gate[0]);
#pragma unroll
    for (int i = 0; i < 4; ++i)
#pragma unroll
        for (int j = 0; j < 4; ++j)
#pragma unroll
            for (int rr = 0; rr < 4; ++rr) {
                int gr = m0 + wm + i * 16 + quad * 4 + rr;
                int gc = n0 + wn + j * 16 + ml;
                out[(size_t)gr * 2048 + gc] = acc[i][j][rr] * scl;
            }
}

// ---------------- MFMA attention: 8 tokens x 1 group per wave, K/V direct from L2 ----------------
// K/V staging removed (was an identity map; kb/vt are 0.5 MB each, L2-resident).
// LDS = p_lds (2.6 KB) only -> attn blocks no longer LDS-occupancy-bound (7 -> ~28/CU).
// Math path identical to the verified staged version (validated in fused R3 run).
__global__ void __launch_bounds__(64)
attn_mfma_kernel(const u16* __restrict__ qb, const u16* __restrict__ kb,
                 const u16* __restrict__ vt, const int* __restrict__ sorted,
                 const int4* __restrict__ tiles, const int* __restrict__ ntiles,
                 u16* __restrict__ yb)
{
    const int tile = blockIdx.x;
    if (tile >= *ntiles) return;
    const int g = blockIdx.y;
    const int4 td = tiles[tile];
    const int bucket = td.x, start = td.y, cnt = td.z;
    const int lane = threadIdx.x;
    const int ml = lane & 15, quad = lane >> 4;

    __shared__ __align__(16) u16 p_lds[32 * 40];
    __shared__ int tok_s[TTILE];

    if (lane < TTILE) tok_s[lane] = (lane < cnt) ? sorted[start + lane] : -1;
    __syncthreads();

    const u16* ksrc = kb + (size_t)bucket * 32 * 512 + g * 128;
    const u16* vsrc = vt + ((size_t)bucket * 4 + g) * 4096;

    f32x4 sc[2][2];
#pragma unroll
    for (int i = 0; i < 2; ++i)
#pragma unroll
        for (int j = 0; j < 2; ++j) sc[i][j] = (f32x4){0.f, 0.f, 0.f, 0.f};
    const int tokA = tok_s[ml & 7];
    const u16* qrow = qb + (size_t)(tokA >= 0 ? tokA : 0) * 2048 + g * 512 + (ml >> 3) * 128;
#pragma unroll
    for (int s = 0; s < 4; ++s) {
        bf16x8 bfr0 = *(const bf16x8*)(ksrc + (size_t)ml * 512 + s * 32 + quad * 8);
        bf16x8 bfr1 = *(const bf16x8*)(ksrc + (size_t)(16 + ml) * 512 + s * 32 + quad * 8);
#pragma unroll
        for (int i = 0; i < 2; ++i) {
            bf16x8 afr = *(const bf16x8*)(qrow + i * 256 + s * 32 + quad * 8);
            sc[i][0] = __builtin_amdgcn_mfma_f32_16x16x32_bf16(afr, bfr0, sc[i][0], 0, 0, 0);
            sc[i][1] = __builtin_amdgcn_mfma_f32_16x16x32_bf16(afr, bfr1, sc[i][1], 0, 0, 0);
        }
    }

    const float scale = 0.088388347648318447f;   // 1/sqrt(128)
#pragma unroll
    for (int i = 0; i < 2; ++i)
#pragma unroll
        for (int reg = 0; reg < 4; ++reg) {
            float s0 = sc[i][0][reg] * scale;
            float s1 = sc[i][1][reg] * scale;
            float mx = fmaxf(s0, s1);
            mx = fmaxf(mx, __shfl_xor(mx, 1));
            mx = fmaxf(mx, __shfl_xor(mx, 2));
            mx = fmaxf(mx, __shfl_xor(mx, 4));
            mx = fmaxf(mx, __shfl_xor(mx, 8));
            float e0 = __expf(s0 - mx), e1 = __expf(s1 - mx);
            float sm = e0 + e1;
            sm += __shfl_xor(sm, 1);
            sm += __shfl_xor(sm, 2);
            sm += __shfl_xor(sm, 4);
            sm += __shfl_xor(sm, 8);
            float inv = 1.0f / sm;
            int prow = i * 16 + quad * 4 + reg;
            p_lds[prow * 40 + ml]      = f2bf(e0 * inv);
            p_lds[prow * 40 + 16 + ml] = f2bf(e1 * inv);
        }
    __syncthreads();

    bf16x8 pfr[2];
    pfr[0] = *(const bf16x8*)&p_lds[ml * 40 + quad * 8];
    pfr[1] = *(const bf16x8*)&p_lds[(16 + ml) * 40 + quad * 8];
#pragma unroll
    for (int i = 0; i < 2; ++i)
#pragma unroll
        for (int j = 0; j < 8; ++j) {
            bf16x8 vfr = *(const bf16x8*)(vsrc + (size_t)(j * 16 + ml) * 32 + quad * 8);
            f32x4 o = (f32x4){0.f, 0.f, 0.f, 0.f};
            o = __builtin_amdgcn_mfma_f32_16x16x32_bf16(pfr[i], vfr, o, 0, 0, 0);
#pragma unroll
            for (int reg = 0; reg < 4; ++reg) {
                int m = quad * 4 + reg;
                int tok = tok_s[m & 7];
                if (tok >= 0) {
                    int r = i * 2 + (m >> 3);
                    yb[(size_t)tok * 2048 + g * 512 + r * 128 + j * 16 + ml] = f2bf(o[reg]);
                }
            }
        }
}

extern "C" void kernel_launch(void* const* d_in, const int* in_sizes, int n_in,
                              void* d_out, int out_size, void* d_ws, size_t ws_size,
                              hipStream_t stream) {
    const float* x    = (const float*)d_in[0];
    const float* cs   = (const float*)d_in[1];
    const int*   cm   = (const int*)d_in[2];
    const float* Wq   = (const float*)d_in[3];
    const float* Wk   = (const float*)d_in[4];
    const float* Wv   = (const float*)d_in[5];
    const float* Wo   = (const float*)d_in[6];
    const float* gate = (const float*)d_in[7];
    float* out = (float*)d_out;

    // workspace layout (16B aligned). Every GEMM A/Bt panel is followed by
    // mapped workspace (pipelined prefetch overreads <=192 B per row).
    // kvp (16 MB f32 split-K partials) OVERLAYS yb: kvp live only between
    // gemm_qkv and kv_combine; yb written by attn strictly after combine.
    char* w = (char*)d_ws;
    u16* xb   = (u16*)w;  w += (size_t)MROWS * CC * 2;        // 8.4 MB
    u16* wqt  = (u16*)w;  w += (size_t)CC * CC * 2;           // 8.4 MB
    u16* wot  = (u16*)w;  w += (size_t)CC * CC * 2;           // 8.4 MB
    u16* qb   = (u16*)w;  w += (size_t)MROWS * CC * 2;        // 8.4 MB
    u16* csb  = (u16*)w;  w += (size_t)CSROWS * CC * 2;       // 2.1 MB
    u16* wkvt = (u16*)w;  w += (size_t)1024 * CC * 2;         // 4.2 MB
    u16* kb   = (u16*)w;  w += (size_t)CSROWS * 512 * 2;      // 0.5 MB
    u16* vt   = (u16*)w;  w += (size_t)64 * 128 * 32 * 2;     // 0.5 MB
    int* sorted = (int*)w; w += (size_t)MROWS * 4;
    int4* tiles = (int4*)w; w += (size_t)MAXTILES * 16;
    int* ntiles = (int*)w;  w += 4096;
    float* kvp = (float*)w;                                   // 16 MB (8 x 512 x 1024 f32)
    u16* yb = (u16*)w;      w += (size_t)8 * 512 * 1024 * 4;  // yb (8.4 MB) inside kvp region

    // 1) all preprocessing in one launch
    prep_kernel<<<PB_END, 256, 0, stream>>>(x, cs, cm, Wq, Wk, Wv, Wo,
                                            xb, csb, wqt, wkvt, wot,
                                            sorted, tiles, ntiles);
    // 2) q-GEMM (256 blocks, XCD-swizzled) + uniform kv split-K slivers
    gemm_qkv_kernel<<<256, 256, 0, stream>>>(xb, wqt, qb, csb, wkvt, kvp);
    // 2b) kv combine: 8 f32 slices -> kb / vt
    kv_combine_kernel<<<256, 256, 0, stream>>>(kvp, kb, vt);
    // 3) attention (tiny-LDS, K/V direct from L2)
    attn_mfma_kernel<<<dim3(MAXTILES, 4), 64, 0, stream>>>(qb, kb, vt, sorted, tiles, ntiles, yb);
    // 4) out = (y @ Wo) * tanh(gate), 256 blocks XCD-swizzled
    gemm_out_kernel<<<256, 256, 0, stream>>>(yb, wot, out, gate);
}